// Round 1
// 107.975 us; speedup vs baseline: 1.0830x; 1.0830x over previous
//
#include <hip/hip_runtime.h>
#include <hip/hip_bf16.h>
#include <cfloat>
#include <math.h>

#define BB 4
#define NR 180
#define CC 512
#define HH 48
#define WW 48
#define FF (CC*4)      // 2048
#define OO 64
#define EPSV 1e-5f
#define TW_LEVEL ((size_t)BB*HH*WW*CC)   // ushorts per table level = 4,718,592

// ---- ws layout ----
// featB : BB*HW*CC ushort (MAPPED u16 domain)          9.44 MB
// W1T4  : [512][64][4] float (W1T4[k>>2][o][k&3]=W1[o][k])  0.5 MB
// Tw    : 4 levels x [BB][HH][WW][CC] ushort (MAPPED)  37.75 MB
//         level k (1..4): max over cols [x, min(x+2^k, W))
//
// order-preserving map bf16 -> u16:  neg ? ~u : u|0x8000.  max/ReLU become
// unsigned integer max (v_pk_max_u16).

typedef unsigned short us2 __attribute__((ext_vector_type(2)));

__device__ __forceinline__ unsigned pmax(unsigned a, unsigned b) {
    return __builtin_bit_cast(unsigned, __builtin_elementwise_max(
        __builtin_bit_cast(us2, a), __builtin_bit_cast(us2, b)));
}
__device__ __forceinline__ uint4 pmax4(uint4 a, uint4 b) {
    return make_uint4(pmax(a.x,b.x), pmax(a.y,b.y), pmax(a.z,b.z), pmax(a.w,b.w));
}
__device__ __forceinline__ unsigned mapb(float f) {      // float -> mapped u16
    unsigned fu = __float_as_uint(f);
    unsigned u = fu >> 16;
    return (fu >> 31) ? (~u & 0xFFFFu) : (u | 0x8000u);
}
__device__ __forceinline__ void unmap2(unsigned m, float& lo, float& hi) {
    unsigned t = ((~m) >> 15) & 0x00010001u;             // 1 where orig negative
    unsigned u = m ^ (0x80008000u ^ (t * 0x7FFFu));      // per-lane: ^0x8000 / ^0xFFFF
    lo = __uint_as_float(u << 16);
    hi = __uint_as_float(u & 0xffff0000u);
}

// ---------------- Kernel 1: transposes (unchanged) --------------------------
__global__ __launch_bounds__(256) void k_prep(const float* __restrict__ feat,
                                              const float* __restrict__ W1,
                                              ushort* __restrict__ featB,
                                              float* __restrict__ W1T4) {
    __shared__ float tile[32][33];
    int t = threadIdx.x;
    int z = blockIdx.z;

    if (z < 4) {
        const int S = HH * WW;                 // 2304
        int b  = z;
        int s0 = blockIdx.x * 32;              // gridDim.x = 72
        int c0 = blockIdx.y * 32;              // gridDim.y = 16
        const float* src = feat + (size_t)b * CC * S;
        ushort* dst = featB + (size_t)b * S * CC;

        int cl = t >> 3;
        int sx = (t & 7) << 2;
        float4 v = *(const float4*)(src + (size_t)(c0 + cl) * S + s0 + sx);
        tile[cl][sx] = v.x; tile[cl][sx+1] = v.y; tile[cl][sx+2] = v.z; tile[cl][sx+3] = v.w;
        __syncthreads();

        int sl = t >> 3;
        int c4 = (t & 7) << 2;
        unsigned u0 = mapb(tile[c4][sl])   | (mapb(tile[c4+1][sl]) << 16);
        unsigned u1 = mapb(tile[c4+2][sl]) | (mapb(tile[c4+3][sl]) << 16);
        *(uint2*)(dst + (size_t)(s0 + sl) * CC + c0 + c4) = make_uint2(u0, u1);
    } else {
        if (blockIdx.x >= 8) return;
        int kt = blockIdx.y * 8 + blockIdx.x;      // 0..127
        int k0 = (kt >> 1) * 32, o0 = (kt & 1) * 32;
        int tx = t & 31, ty = t >> 5;
        #pragma unroll
        for (int k = 0; k < 4; k++) {
            int row = ty + k * 8;
            tile[row][tx] = W1[(size_t)(o0 + row) * FF + (k0 + tx)];
        }
        __syncthreads();
        #pragma unroll
        for (int k = 0; k < 4; k++) {
            int row = ty + k * 8;
            int kk = k0 + row;
            int o  = o0 + tx;
            W1T4[(size_t)(kk >> 2) * 256 + o * 4 + (kk & 3)] = tile[tx][row];
        }
    }
}

// ---------------- Kernel 2: column-max sparse-table build -------------------
// grid 192 = (b,y) rows; block 256. Level k: T[k][x] = max(T[k-1][x],
// T[k-1][min(x+2^(k-1), W-1)]).  48KB LDS, in-place with reg staging.
__global__ __launch_bounds__(256) void k_tab(const ushort* __restrict__ featB,
                                             ushort* __restrict__ Tw) {
    __shared__ uint4 A[WW][64];               // 48 KB
    int by = blockIdx.x;
    int b = by / HH, y = by % HH;
    int t = threadIdx.x;
    const uint4* src = (const uint4*)(featB + (size_t)((b * HH + y) * WW) * CC);

    #pragma unroll
    for (int i = 0; i < 12; i++) {
        int it = t + i * 256;                 // 3072 uint4s = 48 KB
        A[it >> 6][it & 63] = src[it];
    }
    __syncthreads();

    for (int k = 1; k <= 4; k++) {
        int h = 1 << (k - 1);
        uint4* dst = (uint4*)(Tw + ((size_t)(k - 1) * BB * HH + b * HH + y) * (size_t)(WW * CC));
        uint4 v[12];
        #pragma unroll
        for (int i = 0; i < 12; i++) {
            int it = t + i * 256;
            int x = it >> 6, c = it & 63;
            v[i] = pmax4(A[x][c], A[min(x + h, WW - 1)][c]);
        }
        __syncthreads();
        #pragma unroll
        for (int i = 0; i < 12; i++) {
            int it = t + i * 256;
            A[it >> 6][it & 63] = v[i];
            dst[it] = v[i];
        }
        __syncthreads();
    }
}

// ---------------- Kernel 3: fused ROI pool (table lookups) + BN1 + GEMM + BN2
// grid NR, block 1024 = 4 b-groups x (4 rowgroups g x 64 ch-threads c).
// Each column-segment max = 2 lookups at level floor(log2(len)).
__global__ __launch_bounds__(1024) void k_pg(const ushort* __restrict__ featB,
                                             const ushort* __restrict__ Tw,
                                             const float* __restrict__ rois,
                                             const float* __restrict__ W1T4,
                                             const float* __restrict__ bl1,
                                             const float* __restrict__ g1,
                                             const float* __restrict__ b1,
                                             const float* __restrict__ g2,
                                             const float* __restrict__ b2,
                                             float* __restrict__ out) {
    __shared__ unsigned lu[BB][4][16][65];    // 65 KB (pad 65: conflict-free)
    __shared__ float xs[BB][FF];              // 32 KB
    __shared__ float pd[16][BB][OO];          // 16 KB
    __shared__ float pw[16][OO];              // 4 KB
    __shared__ float part_s[16], part_q[16];
    __shared__ float sm2[4], sq2[4];

    int n = blockIdx.x;
    int tid = threadIdx.x;
    int b  = tid >> 8;                        // batch (wave-uniform)
    int g  = (tid >> 6) & 3;                  // rowgroup (wave-uniform)
    int c  = tid & 63;                        // channel-quad (uint4 = 8 ch)

    // ---- phase A: 2x2 adaptive max pool via column-max tables ----
    const float* roi = rois + ((size_t)b * NR + n) * 4;
    int r0 = (int)(roi[0] * 0.25f);
    int r1 = (int)(roi[1] * 0.25f);
    int r2 = (int)ceilf(roi[2] * 0.25f);
    int r3 = (int)ceilf(roi[3] * 0.25f);
    int hs  = r2 - r0 + 1;
    int wsz = r3 - r1 + 1;
    int eh0 = (hs + 1) >> 1, sh1 = hs >> 1;
    int ew0 = (wsz + 1) >> 1, sw1 = wsz >> 1;

    int len0 = ew0;                           // seg0 cols [r1, r1+ew0)
    int k0 = 31 - __clz(len0);
    int x0a = r1, x0b = r1 + len0 - (1 << k0);
    int len1 = wsz - sw1;                     // seg1 cols [r1+sw1, r1+wsz)
    int k1 = 31 - __clz(len1);
    int x1a = r1 + sw1, x1b = r1 + wsz - (1 << k1);

    const ushort* base0 = (k0 == 0) ? featB : (Tw + (size_t)(k0 - 1) * TW_LEVEL);
    const ushort* base1 = (k1 == 0) ? featB : (Tw + (size_t)(k1 - 1) * TW_LEVEL);

    const uint4 Z = make_uint4(0,0,0,0);      // 0 <= any mapped value
    uint4 q00 = Z, q01 = Z, q10 = Z, q11 = Z;
    for (int L = g; L < hs; L += 4) {
        size_t rowoff = (size_t)((b * HH + r0 + L) * WW) * CC;
        const uint4* p0 = (const uint4*)(base0 + rowoff) + c;
        const uint4* p1 = (const uint4*)(base1 + rowoff) + c;
        uint4 cm0 = pmax4(p0[(size_t)64 * x0a], p0[(size_t)64 * x0b]);
        uint4 cm1 = pmax4(p1[(size_t)64 * x1a], p1[(size_t)64 * x1b]);
        if (L <  eh0) { q00 = pmax4(q00, cm0); q01 = pmax4(q01, cm1); }
        if (L >= sh1) { q10 = pmax4(q10, cm0); q11 = pmax4(q11, cm1); }
    }

    // repack: lu[b][g][j][c], j = jc*2 + oi (jc = ch-in-thread 0..7),
    // uint = packed (oj0, oj1).  Component m covers channels 2m (lo), 2m+1 (hi).
    {
        unsigned* L0 = &lu[b][g][0][c];       // j-stride = 65 uints
        unsigned a, p2;
        a = q00.x; p2 = q01.x;
        L0[ 0*65] = (a & 0xFFFFu) | (p2 << 16);           // ch0, oi0
        L0[ 2*65] = (a >> 16)     | (p2 & 0xFFFF0000u);   // ch1, oi0
        a = q10.x; p2 = q11.x;
        L0[ 1*65] = (a & 0xFFFFu) | (p2 << 16);           // ch0, oi1
        L0[ 3*65] = (a >> 16)     | (p2 & 0xFFFF0000u);   // ch1, oi1
        a = q00.y; p2 = q01.y;
        L0[ 4*65] = (a & 0xFFFFu) | (p2 << 16);
        L0[ 6*65] = (a >> 16)     | (p2 & 0xFFFF0000u);
        a = q10.y; p2 = q11.y;
        L0[ 5*65] = (a & 0xFFFFu) | (p2 << 16);
        L0[ 7*65] = (a >> 16)     | (p2 & 0xFFFF0000u);
        a = q00.z; p2 = q01.z;
        L0[ 8*65] = (a & 0xFFFFu) | (p2 << 16);
        L0[10*65] = (a >> 16)     | (p2 & 0xFFFF0000u);
        a = q10.z; p2 = q11.z;
        L0[ 9*65] = (a & 0xFFFFu) | (p2 << 16);
        L0[11*65] = (a >> 16)     | (p2 & 0xFFFF0000u);
        a = q00.w; p2 = q01.w;
        L0[12*65] = (a & 0xFFFFu) | (p2 << 16);
        L0[14*65] = (a >> 16)     | (p2 & 0xFFFF0000u);
        a = q10.w; p2 = q11.w;
        L0[13*65] = (a & 0xFFFFu) | (p2 << 16);
        L0[15*65] = (a >> 16)     | (p2 & 0xFFFF0000u);
    }
    __syncthreads();

    // ---- phase B1: cross-g reduce + ReLU + unmap + BN1 stats ----
    // thread (bb, s) owns f in [4s,4s+4) and [1024+4s, 1024+4s+4):
    // f = cc*32 + 2*j + oj  with cc = fb>>5, j0 = (fb>>1)&15  => float4 @ fb.
    float s_acc = 0.f, q_acc = 0.f;
    int s  = tid & 255;
    int bb = tid >> 8;
    #pragma unroll
    for (int p = 0; p < 2; p++) {
        int fb = (p << 10) + (s << 2);
        int cc = fb >> 5;
        int j0 = (fb >> 1) & 15;              // even
        unsigned m0 = pmax(pmax(lu[bb][0][j0  ][cc], lu[bb][1][j0  ][cc]),
                           pmax(lu[bb][2][j0  ][cc], lu[bb][3][j0  ][cc]));
        unsigned m1 = pmax(pmax(lu[bb][0][j0+1][cc], lu[bb][1][j0+1][cc]),
                           pmax(lu[bb][2][j0+1][cc], lu[bb][3][j0+1][cc]));
        m0 = pmax(m0, 0x80008000u);           // ReLU: mapped(+0) = 0x8000
        m1 = pmax(m1, 0x80008000u);
        float v0, v1, v2, v3;
        unmap2(m0, v0, v1);
        unmap2(m1, v2, v3);
        *(float4*)&xs[bb][fb] = make_float4(v0, v1, v2, v3);
        s_acc += v0 + v1 + v2 + v3;
        q_acc += v0*v0 + v1*v1 + v2*v2 + v3*v3;
    }
    for (int off = 32; off; off >>= 1) {
        s_acc += __shfl_down(s_acc, off);
        q_acc += __shfl_down(q_acc, off);
    }
    if ((tid & 63) == 0) { part_s[tid >> 6] = s_acc; part_q[tid >> 6] = q_acc; }
    __syncthreads();
    float ts = 0.f, tq = 0.f;
    #pragma unroll
    for (int i = 0; i < 16; i++) { ts += part_s[i]; tq += part_q[i]; }
    const float inv1 = 1.f / (float)(BB * FF);
    float mean = ts * inv1;
    float var  = tq * inv1 - mean * mean;
    float a1n  = g1[n] * rsqrtf(var + EPSV);
    float c1n  = b1[n] - mean * a1n;

    // ---- phase B2: GEMM (BN1 hoisted via wsum) ----
    int sc = tid >> 6;
    int o  = tid & 63;
    int k4a = sc << 5;
    float a0 = 0.f, a1 = 0.f, a2 = 0.f, a3 = 0.f, wsum = 0.f;
    #pragma unroll 4
    for (int k4 = k4a; k4 < k4a + 32; k4++) {
        float4 w4 = *(const float4*)(W1T4 + (size_t)k4 * 256 + o * 4);
        float4 x0 = *(const float4*)&xs[0][k4 << 2];
        float4 x1 = *(const float4*)&xs[1][k4 << 2];
        float4 x2 = *(const float4*)&xs[2][k4 << 2];
        float4 x3 = *(const float4*)&xs[3][k4 << 2];
        wsum += w4.x + w4.y + w4.z + w4.w;
        a0 += w4.x*x0.x + w4.y*x0.y + w4.z*x0.z + w4.w*x0.w;
        a1 += w4.x*x1.x + w4.y*x1.y + w4.z*x1.z + w4.w*x1.w;
        a2 += w4.x*x2.x + w4.y*x2.y + w4.z*x2.z + w4.w*x2.w;
        a3 += w4.x*x3.x + w4.y*x3.y + w4.z*x3.z + w4.w*x3.w;
    }
    pd[sc][0][o] = a0; pd[sc][1][o] = a1; pd[sc][2][o] = a2; pd[sc][3][o] = a3;
    pw[sc][o] = wsum;
    __syncthreads();

    // ---- phase B3: BN2 + store ----
    float y = 0.f;
    int bo = tid >> 6;
    if (tid < 256) {
        float dot = 0.f, wsm = 0.f;
        #pragma unroll
        for (int ss = 0; ss < 16; ss++) { dot += pd[ss][bo][o]; wsm += pw[ss][o]; }
        y = a1n * dot + c1n * wsm + bl1[o];
        float rs = y, rq = y * y;
        for (int off = 32; off; off >>= 1) {
            rs += __shfl_down(rs, off);
            rq += __shfl_down(rq, off);
        }
        if (o == 0) { sm2[bo] = rs; sq2[bo] = rq; }
    }
    __syncthreads();
    if (tid < 256) {
        float sm  = sm2[0] + sm2[1] + sm2[2] + sm2[3];
        float sqm = sq2[0] + sq2[1] + sq2[2] + sq2[3];
        const float inv2 = 1.f / 256.f;
        float mean2 = sm * inv2;
        float var2  = sqm * inv2 - mean2 * mean2;
        float r2s = rsqrtf(var2 + EPSV);
        out[((size_t)bo * NR + n) * OO + o] = (y - mean2) * r2s * g2[n] + b2[n];
    }
}

extern "C" void kernel_launch(void* const* d_in, const int* in_sizes, int n_in,
                              void* d_out, int out_size, void* d_ws, size_t ws_size,
                              hipStream_t stream) {
    const float* feat = (const float*)d_in[0];
    const float* rois = (const float*)d_in[1];
    const float* g1   = (const float*)d_in[2];
    const float* b1   = (const float*)d_in[3];
    const float* W1   = (const float*)d_in[4];
    const float* bl1  = (const float*)d_in[5];
    const float* g2   = (const float*)d_in[6];
    const float* b2   = (const float*)d_in[7];
    float* out = (float*)d_out;

    ushort* featB = (ushort*)d_ws;                        // 9.44 MB (mapped u16)
    float*  W1T4  = (float*)(featB + (size_t)BB*HH*WW*CC);// 0.5 MB
    ushort* Tw    = (ushort*)(W1T4 + (size_t)OO*FF);      // 37.75 MB (4 levels)

    k_prep<<<dim3(72, 16, 5), 256, 0, stream>>>(feat, W1, featB, W1T4);
    k_tab<<<dim3(BB * HH), 256, 0, stream>>>(featB, Tw);
    k_pg<<<dim3(NR), 1024, 0, stream>>>(featB, Tw, rois, W1T4, bl1, g1, b1, g2, b2, out);
}